// Round 5
// baseline (16.867 us; speedup 1.0000x reference)
//
#include <hip/hip_runtime.h>
#include <utility>

// Geometric product in Cl(3,2,1), DIM=64.
// out[n,k] = sum_a sign(a, a^k) * x[n,a] * y[n,a^k]
//
// xor-nibble decomposition: k = 4*kk + q, a = 4*ah + al =>
//   b = a^k = 4*(ah^kk) + (al^q)
// Nibble-plane LDS layout: nib[al][row*20 + ah] (pad 16->20 floats/row so
// ds_read_b128 lane stride is 80 B -> start banks cycle all 32 banks every
// 8 lanes -> conflict-free). Per (thread, al-group): 4+4 ds_read_b128 pull
// xv[16], yr[16]; 16x16 xor-convolution with compile-time signs.
//
// T=2 tiles/block with reg-staged prefetch (T14): tile1's global loads are
// issued before tile0's compute; reg->LDS writes land after the barrier.
// amdgpu_waves_per_eu(2,4): lift the allocator's default 8-waves/SIMD
// 64-VGPR target (the hidden spill cause of rounds 1-3); grid gives only
// 2 blocks/CU (8 waves/CU) so minimum-2-waves costs nothing.

__host__ __device__ constexpr int popc6(int v) {
  int c = 0;
  for (int i = 0; i < 6; ++i) c += (v >> i) & 1;
  return c;
}

// Faithful to reference _cayley_tables(3,2,1): swap parity, (-1) per shared
// negative dim (bits 3,4), annihilation on shared null dim (bit 5).
__host__ __device__ constexpr float sign_ab(int a, int b) {
  int sw = 0;
  for (int bit = 0; bit < 6; ++bit)
    if ((a >> bit) & 1) sw += popc6(b & ((1 << bit) - 1));
  float s = (sw & 1) ? -1.0f : 1.0f;
  if (popc6(a & b & 0x18) & 1) s = -s;
  if (a & b & 0x20) s = 0.0f;
  return s;
}

// ---- compile-time FMA folds (proven in round 4: guaranteed constant
// indices, no runtime-indexed arrays, no scratch) ----
template <int Q, int ALO, int AHI, int KK>
__device__ __forceinline__ void term(const float (&xv)[16], const float (&yr)[16],
                                     float (&acc)[16]) {
  constexpr int a = 4 * AHI + ALO;
  constexpr int b = 4 * (AHI ^ KK) + (ALO ^ Q);
  constexpr float sg = sign_ab(a, b);
  if constexpr (sg > 0.0f)      acc[KK] = fmaf( xv[AHI], yr[AHI ^ KK], acc[KK]);
  else if constexpr (sg < 0.0f) acc[KK] = fmaf(-xv[AHI], yr[AHI ^ KK], acc[KK]);
}

template <int Q, int ALO, int AHI, int... KK>
__device__ __forceinline__ void terms(const float (&xv)[16], const float (&yr)[16],
                                      float (&acc)[16], std::integer_sequence<int, KK...>) {
  (term<Q, ALO, AHI, KK>(xv, yr, acc), ...);
}

template <int Q, int ALO, int... AHI>
__device__ __forceinline__ void grp_fma(const float (&xv)[16], const float (&yr)[16],
                                        float (&acc)[16], std::integer_sequence<int, AHI...>) {
  (terms<Q, ALO, AHI>(xv, yr, acc, std::make_integer_sequence<int, 16>{}), ...);
}

// One al-group: pull xv[16] from x-plane ALO and yr[16] from y-plane ALO^Q
// (4x ds_read_b128 each, conflict-free), then 16x16 constant-sign FMAs.
template <int Q, int ALO>
__device__ __forceinline__ void group(const float4* __restrict__ xnib4,
                                      const float4* __restrict__ ynib4,
                                      int lane, float (&acc)[16]) {
  constexpr int c = ALO ^ Q;  // y plane index
  float xv[16], yr[16];
#pragma unroll
  for (int u = 0; u < 4; ++u) {
    const float4 tx = xnib4[ALO * 320 + lane * 5 + u];  // plane stride 320 f4
    const float4 ty = ynib4[c * 320 + lane * 5 + u];
    xv[4 * u + 0] = tx.x; xv[4 * u + 1] = tx.y; xv[4 * u + 2] = tx.z; xv[4 * u + 3] = tx.w;
    yr[4 * u + 0] = ty.x; yr[4 * u + 1] = ty.y; yr[4 * u + 2] = ty.z; yr[4 * u + 3] = ty.w;
  }
  grp_fma<Q, ALO>(xv, yr, acc, std::make_integer_sequence<int, 16>{});
}

template <int Q>
__device__ __forceinline__ void compute(const float4* __restrict__ xnib4,
                                        const float4* __restrict__ ynib4,
                                        int lane, float (&acc)[16]) {
  group<Q, 0>(xnib4, ynib4, lane, acc);
  group<Q, 1>(xnib4, ynib4, lane, acc);
  group<Q, 2>(xnib4, ynib4, lane, acc);
  group<Q, 3>(xnib4, ynib4, lane, acc);
}

__global__ __launch_bounds__(256) __attribute__((amdgpu_waves_per_eu(2, 4)))
void clgp_kernel(const float* __restrict__ xg, const float* __restrict__ yg,
                 float* __restrict__ og) {
  // LDS: two nibble-plane tensors (4 planes x 64 rows x 5 float4 = 20 KB each)
  // + output transpose buffer (64x65 floats, 16.6 KB). Total 57.6 KB -> 2 blocks/CU.
  __shared__ float4 xnib4[4 * 64 * 5];
  __shared__ float4 ynib4[4 * 64 * 5];
  __shared__ float obuf[64 * 65];
  float* xnib = (float*)xnib4;
  float* ynib = (float*)ynib4;

  const int t = threadIdx.x;
  const int lane = t & 63;  // batch row within tile
  const int q = t >> 6;     // wave id = k residue class mod 4 (wave-uniform)
  const long base0 = (long)blockIdx.x * 2 * 4096;  // 2 tiles of 64x64 floats

  // ---- prologue: stage tile 0 (coalesced float4 -> plane-scatter writes) ----
  {
    const float4* x4 = (const float4*)(xg + base0);
    const float4* y4 = (const float4*)(yg + base0);
    float4 rx[4], ry[4];
#pragma unroll
    for (int p = 0; p < 4; ++p) { rx[p] = x4[t + p * 256]; ry[p] = y4[t + p * 256]; }
#pragma unroll
    for (int p = 0; p < 4; ++p) {
      const int v = t + p * 256;
      const int off = (v >> 4) * 20 + (v & 15);  // row*20 + ah
      xnib[0 * 1280 + off] = rx[p].x; xnib[1 * 1280 + off] = rx[p].y;
      xnib[2 * 1280 + off] = rx[p].z; xnib[3 * 1280 + off] = rx[p].w;
      ynib[0 * 1280 + off] = ry[p].x; ynib[1 * 1280 + off] = ry[p].y;
      ynib[2 * 1280 + off] = ry[p].z; ynib[3 * 1280 + off] = ry[p].w;
    }
  }
  __syncthreads();

#pragma unroll
  for (int tt = 0; tt < 2; ++tt) {
    // ---- A: issue next tile's global loads (latency hides under compute) ----
    float4 px[4], py[4];
    if (tt == 0) {
      const float4* x4n = (const float4*)(xg + base0 + 4096);
      const float4* y4n = (const float4*)(yg + base0 + 4096);
#pragma unroll
      for (int p = 0; p < 4; ++p) { px[p] = x4n[t + p * 256]; py[p] = y4n[t + p * 256]; }
    }

    // ---- compute current tile ----
    float acc[16];
#pragma unroll
    for (int i = 0; i < 16; ++i) acc[i] = 0.0f;
    switch (q) {  // wave-uniform -> no divergence
      case 0:  compute<0>(xnib4, ynib4, lane, acc); break;
      case 1:  compute<1>(xnib4, ynib4, lane, acc); break;
      case 2:  compute<2>(xnib4, ynib4, lane, acc); break;
      default: compute<3>(xnib4, ynib4, lane, acc); break;
    }
    __syncthreads();  // B: compute reads done -> x/y planes reusable, obuf writable

    // out-transpose: acc[kk] -> obuf[row][4kk+q]  (65-stride: 2-way bank = free)
#pragma unroll
    for (int kk = 0; kk < 16; ++kk) obuf[lane * 65 + 4 * kk + q] = acc[kk];

    // stage next tile (compiler inserts vmcnt wait on px/py here)
    if (tt == 0) {
#pragma unroll
      for (int p = 0; p < 4; ++p) {
        const int v = t + p * 256;
        const int off = (v >> 4) * 20 + (v & 15);
        xnib[0 * 1280 + off] = px[p].x; xnib[1 * 1280 + off] = px[p].y;
        xnib[2 * 1280 + off] = px[p].z; xnib[3 * 1280 + off] = px[p].w;
        ynib[0 * 1280 + off] = py[p].x; ynib[1 * 1280 + off] = py[p].y;
        ynib[2 * 1280 + off] = py[p].z; ynib[3 * 1280 + off] = py[p].w;
      }
    }
    __syncthreads();  // C: obuf ready (and next tile staged)

    // ---- store current tile: coalesced float4 ----
    float4* o4 = (float4*)(og + base0 + (long)tt * 4096);
#pragma unroll
    for (int p = 0; p < 4; ++p) {
      const int v = t + p * 256;
      const int w = (v >> 4) * 65 + 4 * (v & 15);
      float4 o;
      o.x = obuf[w + 0]; o.y = obuf[w + 1]; o.z = obuf[w + 2]; o.w = obuf[w + 3];
      o4[v] = o;
    }
  }
}

extern "C" void kernel_launch(void* const* d_in, const int* in_sizes, int n_in,
                              void* d_out, int out_size, void* d_ws, size_t ws_size,
                              hipStream_t stream) {
  const float* x = (const float*)d_in[0];
  const float* y = (const float*)d_in[1];
  float* out = (float*)d_out;
  const int n_batch = in_sizes[0] / 64;
  const int grid = n_batch / 128;  // 2 tiles of 64 rows per block -> 512 blocks
  clgp_kernel<<<grid, 256, 0, stream>>>(x, y, out);
}

// Round 6
// 16.853 us; speedup vs baseline: 1.0008x; 1.0008x over previous
//
#include <hip/hip_runtime.h>
#include <utility>

// Geometric product in Cl(3,2,1), DIM=64.
// out[n,k] = sum_a sign(a, a^k) * x[n,a] * y[n,a^k]
//
// xor-nibble decomposition: k = 4*kk + q, a = 4*ah + al =>
//   b = a^k = 4*(ah^kk) + (al^q)
// Nibble-plane LDS layout: nib[al][row*20 + ah] (pad 16->20 floats/row so
// ds_read_b128 lane stride is 80 B -> start banks cycle all 32 banks every
// 8 lanes -> conflict-free). Per (thread, al-group): 4+4 ds_read_b128 pull
// xv[16], yr[16]; 16x16 xor-convolution with compile-time signs.
//
// T=2 tiles/block with reg-staged prefetch (T14): tile1's global loads are
// issued before tile0's compute; reg->LDS writes land after the barrier.
//
// ROUND 6 CHANGE (single variable): __launch_bounds__(256, 2) instead of
// amdgpu_waves_per_eu(2,4). Rounds 1-3 proved the allocator pins VGPR=64
// (8 waves/SIMD target) and SPILLS anything above; the round-5 prefetch
// needs ~90 live regs, so if the attr was ignored, px/py went to scratch
// and the prefetch was a wash (observed: 16.6 -> 16.9, no change).
// launch_bounds(256,2) = min 2 waves/EU -> 256-VGPR ceiling; grid gives
// only 2 blocks/CU (2 waves/SIMD) so the floor costs nothing.

__host__ __device__ constexpr int popc6(int v) {
  int c = 0;
  for (int i = 0; i < 6; ++i) c += (v >> i) & 1;
  return c;
}

// Faithful to reference _cayley_tables(3,2,1): swap parity, (-1) per shared
// negative dim (bits 3,4), annihilation on shared null dim (bit 5).
__host__ __device__ constexpr float sign_ab(int a, int b) {
  int sw = 0;
  for (int bit = 0; bit < 6; ++bit)
    if ((a >> bit) & 1) sw += popc6(b & ((1 << bit) - 1));
  float s = (sw & 1) ? -1.0f : 1.0f;
  if (popc6(a & b & 0x18) & 1) s = -s;
  if (a & b & 0x20) s = 0.0f;
  return s;
}

// ---- compile-time FMA folds (guaranteed constant indices, no scratch) ----
template <int Q, int ALO, int AHI, int KK>
__device__ __forceinline__ void term(const float (&xv)[16], const float (&yr)[16],
                                     float (&acc)[16]) {
  constexpr int a = 4 * AHI + ALO;
  constexpr int b = 4 * (AHI ^ KK) + (ALO ^ Q);
  constexpr float sg = sign_ab(a, b);
  if constexpr (sg > 0.0f)      acc[KK] = fmaf( xv[AHI], yr[AHI ^ KK], acc[KK]);
  else if constexpr (sg < 0.0f) acc[KK] = fmaf(-xv[AHI], yr[AHI ^ KK], acc[KK]);
}

template <int Q, int ALO, int AHI, int... KK>
__device__ __forceinline__ void terms(const float (&xv)[16], const float (&yr)[16],
                                      float (&acc)[16], std::integer_sequence<int, KK...>) {
  (term<Q, ALO, AHI, KK>(xv, yr, acc), ...);
}

template <int Q, int ALO, int... AHI>
__device__ __forceinline__ void grp_fma(const float (&xv)[16], const float (&yr)[16],
                                        float (&acc)[16], std::integer_sequence<int, AHI...>) {
  (terms<Q, ALO, AHI>(xv, yr, acc, std::make_integer_sequence<int, 16>{}), ...);
}

// One al-group: pull xv[16] from x-plane ALO and yr[16] from y-plane ALO^Q
// (4x ds_read_b128 each, conflict-free), then 16x16 constant-sign FMAs.
template <int Q, int ALO>
__device__ __forceinline__ void group(const float4* __restrict__ xnib4,
                                      const float4* __restrict__ ynib4,
                                      int lane, float (&acc)[16]) {
  constexpr int c = ALO ^ Q;  // y plane index
  float xv[16], yr[16];
#pragma unroll
  for (int u = 0; u < 4; ++u) {
    const float4 tx = xnib4[ALO * 320 + lane * 5 + u];  // plane stride 320 f4
    const float4 ty = ynib4[c * 320 + lane * 5 + u];
    xv[4 * u + 0] = tx.x; xv[4 * u + 1] = tx.y; xv[4 * u + 2] = tx.z; xv[4 * u + 3] = tx.w;
    yr[4 * u + 0] = ty.x; yr[4 * u + 1] = ty.y; yr[4 * u + 2] = ty.z; yr[4 * u + 3] = ty.w;
  }
  grp_fma<Q, ALO>(xv, yr, acc, std::make_integer_sequence<int, 16>{});
}

template <int Q>
__device__ __forceinline__ void compute(const float4* __restrict__ xnib4,
                                        const float4* __restrict__ ynib4,
                                        int lane, float (&acc)[16]) {
  group<Q, 0>(xnib4, ynib4, lane, acc);
  group<Q, 1>(xnib4, ynib4, lane, acc);
  group<Q, 2>(xnib4, ynib4, lane, acc);
  group<Q, 3>(xnib4, ynib4, lane, acc);
}

__global__ __launch_bounds__(256, 2)
void clgp_kernel(const float* __restrict__ xg, const float* __restrict__ yg,
                 float* __restrict__ og) {
  // LDS: two nibble-plane tensors (4 planes x 64 rows x 5 float4 = 20 KB each)
  // + output transpose buffer (64x65 floats, 16.6 KB). Total 57.6 KB -> 2 blocks/CU.
  __shared__ float4 xnib4[4 * 64 * 5];
  __shared__ float4 ynib4[4 * 64 * 5];
  __shared__ float obuf[64 * 65];
  float* xnib = (float*)xnib4;
  float* ynib = (float*)ynib4;

  const int t = threadIdx.x;
  const int lane = t & 63;  // batch row within tile
  const int q = t >> 6;     // wave id = k residue class mod 4 (wave-uniform)
  const long base0 = (long)blockIdx.x * 2 * 4096;  // 2 tiles of 64x64 floats

  // ---- prologue: stage tile 0 (coalesced float4 -> plane-scatter writes) ----
  {
    const float4* x4 = (const float4*)(xg + base0);
    const float4* y4 = (const float4*)(yg + base0);
    float4 rx[4], ry[4];
#pragma unroll
    for (int p = 0; p < 4; ++p) { rx[p] = x4[t + p * 256]; ry[p] = y4[t + p * 256]; }
#pragma unroll
    for (int p = 0; p < 4; ++p) {
      const int v = t + p * 256;
      const int off = (v >> 4) * 20 + (v & 15);  // row*20 + ah
      xnib[0 * 1280 + off] = rx[p].x; xnib[1 * 1280 + off] = rx[p].y;
      xnib[2 * 1280 + off] = rx[p].z; xnib[3 * 1280 + off] = rx[p].w;
      ynib[0 * 1280 + off] = ry[p].x; ynib[1 * 1280 + off] = ry[p].y;
      ynib[2 * 1280 + off] = ry[p].z; ynib[3 * 1280 + off] = ry[p].w;
    }
  }
  __syncthreads();

#pragma unroll
  for (int tt = 0; tt < 2; ++tt) {
    // ---- A: issue next tile's global loads (latency hides under compute) ----
    float4 px[4], py[4];
    if (tt == 0) {
      const float4* x4n = (const float4*)(xg + base0 + 4096);
      const float4* y4n = (const float4*)(yg + base0 + 4096);
#pragma unroll
      for (int p = 0; p < 4; ++p) { px[p] = x4n[t + p * 256]; py[p] = y4n[t + p * 256]; }
    }

    // ---- compute current tile ----
    float acc[16];
#pragma unroll
    for (int i = 0; i < 16; ++i) acc[i] = 0.0f;
    switch (q) {  // wave-uniform -> no divergence
      case 0:  compute<0>(xnib4, ynib4, lane, acc); break;
      case 1:  compute<1>(xnib4, ynib4, lane, acc); break;
      case 2:  compute<2>(xnib4, ynib4, lane, acc); break;
      default: compute<3>(xnib4, ynib4, lane, acc); break;
    }
    __syncthreads();  // B: compute reads done -> x/y planes reusable, obuf writable

    // out-transpose: acc[kk] -> obuf[row][4kk+q]  (65-stride: 2-way bank = free)
#pragma unroll
    for (int kk = 0; kk < 16; ++kk) obuf[lane * 65 + 4 * kk + q] = acc[kk];

    // stage next tile (compiler inserts vmcnt wait on px/py here)
    if (tt == 0) {
#pragma unroll
      for (int p = 0; p < 4; ++p) {
        const int v = t + p * 256;
        const int off = (v >> 4) * 20 + (v & 15);
        xnib[0 * 1280 + off] = px[p].x; xnib[1 * 1280 + off] = px[p].y;
        xnib[2 * 1280 + off] = px[p].z; xnib[3 * 1280 + off] = px[p].w;
        ynib[0 * 1280 + off] = py[p].x; ynib[1 * 1280 + off] = py[p].y;
        ynib[2 * 1280 + off] = py[p].z; ynib[3 * 1280 + off] = py[p].w;
      }
    }
    __syncthreads();  // C: obuf ready (and next tile staged)

    // ---- store current tile: coalesced float4 ----
    float4* o4 = (float4*)(og + base0 + (long)tt * 4096);
#pragma unroll
    for (int p = 0; p < 4; ++p) {
      const int v = t + p * 256;
      const int w = (v >> 4) * 65 + 4 * (v & 15);
      float4 o;
      o.x = obuf[w + 0]; o.y = obuf[w + 1]; o.z = obuf[w + 2]; o.w = obuf[w + 3];
      o4[v] = o;
    }
  }
}

extern "C" void kernel_launch(void* const* d_in, const int* in_sizes, int n_in,
                              void* d_out, int out_size, void* d_ws, size_t ws_size,
                              hipStream_t stream) {
  const float* x = (const float*)d_in[0];
  const float* y = (const float*)d_in[1];
  float* out = (float*)d_out;
  const int n_batch = in_sizes[0] / 64;
  const int grid = n_batch / 128;  // 2 tiles of 64 rows per block -> 512 blocks
  clgp_kernel<<<grid, 256, 0, stream>>>(x, y, out);
}